// Round 1
// baseline (210.991 us; speedup 1.0000x reference)
//
#include <hip/hip_runtime.h>
#include <math.h>

#define SPB 3136      // spatial positions per batch (56*56)
#define NB 8
#define EPS 1e-5f

typedef unsigned short u16;
typedef __attribute__((ext_vector_type(8))) short short8;
typedef __attribute__((ext_vector_type(4))) float float4v;

__device__ __forceinline__ float b2f(u16 v){ unsigned u=((unsigned)v)<<16; float f; __builtin_memcpy(&f,&u,4); return f; }
__device__ __forceinline__ u16 f2b(float f){ unsigned u; __builtin_memcpy(&u,&f,4); u += 0x7fffu + ((u>>16)&1u); return (u16)(u>>16); }
__device__ __forceinline__ float gelu_f(float z){ return 0.5f*z*(1.0f+erff(z*0.70710678118654752f)); }

// ---- fold BN constants: s = g/sqrt(v+eps), t = b*s + be - m*s ----
// cst layout: s1[256] t1[256] sg[512] tg[512] s2[256] t2[256]
__global__ void prep_consts_k(const float* b1,const float* g1,const float* be1,const float* m1,const float* v1,
                              const float* bg,const float* gg,const float* beg,const float* mg,const float* vg,
                              const float* b2,const float* g2,const float* be2,const float* m2,const float* v2,
                              float* cst){
  int i = threadIdx.x;
  if (i < 256) {
    float s = g1[i]*rsqrtf(v1[i]+EPS);
    cst[i] = s; cst[256+i] = b1[i]*s + be1[i] - m1[i]*s;
    float s2 = g2[i]*rsqrtf(v2[i]+EPS);
    cst[1536+i] = s2; cst[1792+i] = b2[i]*s2 + be2[i] - m2[i]*s2;
  }
  float s = gg[i]*rsqrtf(vg[i]+EPS);
  cst[512+i] = s; cst[1024+i] = bg[i]*s + beg[i] - mg[i]*s;
}

__global__ void conv_w_k(const float* __restrict__ w1,const float* __restrict__ wg,const float* __restrict__ w2,
                         u16* __restrict__ w1b,u16* __restrict__ wgb,u16* __restrict__ w2b){
  int i = blockIdx.x*256 + threadIdx.x;
  if (i < 65536)  w1b[i] = f2b(w1[i]);
  if (i < 262144) wgb[i] = f2b(wg[i]);
  if (i < 131072) w2b[i] = f2b(w2[i]);
}

// x [b][c][s] fp32 -> xt [b][s][c] bf16
__global__ void transpose_x_k(const float* __restrict__ x, u16* __restrict__ xt){
  __shared__ float t[32][33];
  int b = blockIdx.z, ct = blockIdx.y, st = blockIdx.x;
  int ts = threadIdx.x, tc = threadIdx.y;
  #pragma unroll
  for (int i=0;i<4;i++){
    int c = tc + i*8;
    t[c][ts] = x[((size_t)(b*256 + ct*32 + c))*SPB + st*32 + ts];
  }
  __syncthreads();
  #pragma unroll
  for (int i=0;i<4;i++){
    int r = tc + i*8;
    xt[((size_t)(b*SPB + st*32 + r))*256 + ct*32 + ts] = f2b(t[ts][r]);
  }
}

// per (b,y): min over x of h, split by x-parity.  h = cat[...,0:256]
__global__ void rowmin_k(const u16* __restrict__ cat, float* __restrict__ rmin){
  int b = blockIdx.x/56, y = blockIdx.x%56, c = threadIdx.x;
  float mE=3.4e38f, mO=3.4e38f;
  const u16* base = cat + ((size_t)(b*SPB + y*56))*512 + c;
  for (int x=0;x<56;x+=2){
    mE = fminf(mE, b2f(base[(size_t)x*512]));
    mO = fminf(mO, b2f(base[(size_t)(x+1)*512]));
  }
  rmin[((size_t)(b*2+0)*56 + y)*256 + c]=mE;
  rmin[((size_t)(b*2+1)*56 + y)*256 + c]=mO;
}
// per (b,x): min over y of h, split by y-parity
__global__ void colmin_k(const u16* __restrict__ cat, float* __restrict__ cmin){
  int b = blockIdx.x/56, x = blockIdx.x%56, c = threadIdx.x;
  float mE=3.4e38f, mO=3.4e38f;
  const u16* base = cat + ((size_t)(b*SPB + x))*512 + c;
  for (int y=0;y<56;y+=2){
    mE = fminf(mE, b2f(base[(size_t)(y*56)*512]));
    mO = fminf(mO, b2f(base[(size_t)((y+1)*56)*512]));
  }
  cmin[((size_t)(b*2+0)*56 + x)*256 + c]=mE;
  cmin[((size_t)(b*2+1)*56 + x)*256 + c]=mO;
}
// xj = max(0, h - min(colMinP[y%2][x], rowMinP[x%2][y])) -> cat[...,256:512]
__global__ void xj_k(u16* __restrict__ cat, const float* __restrict__ rmin, const float* __restrict__ cmin){
  int b = blockIdx.y, s = blockIdx.x, c = threadIdx.x;
  int y = s/56, x = s%56;
  size_t idx = ((size_t)(b*SPB + s))*512;
  float h = b2f(cat[idx + c]);
  float m = fminf(cmin[((size_t)(b*2+(y&1))*56 + x)*256 + c],
                  rmin[((size_t)(b*2+(x&1))*56 + y)*256 + c]);
  cat[idx + 256 + c] = f2b(fmaxf(0.0f, h - m));
}

// GEMM: D[s][o] = sum_k Ain[b][s][k] * Wt[o][k]; tiles BM=64(s) x BN=128(o) x BK=32
// EPI 1: bf16( acc*s + t )           -> out stride 512 (cat_t)
// EPI 2: bf16( gelu(acc*s + t) )     -> out stride 512 (g_t)
// EPI 3: fp32( acc*s + t + x[b][o][s] ) -> out [b][256][s]
template<int KTOT, int EPI>
__global__ __launch_bounds__(256) void gemm_k(
    const u16* __restrict__ Ain, const u16* __restrict__ Wt,
    const float* __restrict__ scale, const float* __restrict__ bias,
    void* __restrict__ outp, const float* __restrict__ resid)
{
  __shared__ __align__(16) u16 smem[8192];          // 16 KB
  u16* As = smem;            // [64][40] padded (32 payload + 8 pad)
  u16* Bs = smem + 64*40;    // [128][40]
  const int tid = threadIdx.x;
  const int b = blockIdx.z;
  const int s0 = blockIdx.x * 64;
  const int o0 = blockIdx.y * 128;
  const int lane = tid & 63, wid = tid >> 6;
  const int quad = lane >> 4, l16 = lane & 15;
  const int wm = wid & 1, wn = wid >> 1;

  float4v acc[2][4];
  #pragma unroll
  for (int i=0;i<2;i++)
    #pragma unroll
    for (int j=0;j<4;j++) acc[i][j] = (float4v){0.f,0.f,0.f,0.f};

  const int arow = tid >> 2, aoff = (tid & 3)*8;
  const u16* Ab  = Ain + ((size_t)(b*SPB + s0 + arow))*KTOT + aoff;
  const u16* Wb0 = Wt + ((size_t)(o0 + arow))*KTOT + aoff;
  const u16* Wb1 = Wt + ((size_t)(o0 + 64 + arow))*KTOT + aoff;
  u16* Asw  = As + arow*40 + aoff;
  u16* Bsw0 = Bs + arow*40 + aoff;
  u16* Bsw1 = Bs + (64+arow)*40 + aoff;

  for (int kt = 0; kt < KTOT; kt += 32) {
    *(uint4*)Asw  = *(const uint4*)(Ab + kt);
    *(uint4*)Bsw0 = *(const uint4*)(Wb0 + kt);
    *(uint4*)Bsw1 = *(const uint4*)(Wb1 + kt);
    __syncthreads();
    short8 af[2], bfr[4];
    #pragma unroll
    for (int im=0;im<2;im++) af[im] = *(const short8*)&As[(wm*32+im*16+l16)*40 + quad*8];
    #pragma unroll
    for (int in=0;in<4;in++) bfr[in] = *(const short8*)&Bs[(wn*64+in*16+l16)*40 + quad*8];
    #pragma unroll
    for (int im=0;im<2;im++)
      #pragma unroll
      for (int in=0;in<4;in++)
        acc[im][in] = __builtin_amdgcn_mfma_f32_16x16x32_bf16(af[im], bfr[in], acc[im][in], 0, 0, 0);
    __syncthreads();
  }

  if (EPI == 1 || EPI == 2) {
    u16* tile = smem; // [64 s][128 o]
    #pragma unroll
    for (int im=0;im<2;im++)
      #pragma unroll
      for (int in=0;in<4;in++){
        int ol = wn*64 + in*16 + l16;
        float sc = scale[o0+ol], bi = bias[o0+ol];
        #pragma unroll
        for (int r=0;r<4;r++){
          float v = acc[im][in][r]*sc + bi;
          if (EPI==2) v = gelu_f(v);
          tile[(wm*32+im*16+quad*4+r)*128 + ol] = f2b(v);
        }
      }
    __syncthreads();
    u16* op = (u16*)outp;
    #pragma unroll
    for (int p=0;p<4;p++){
      int chunk = p*256 + tid;
      int row = chunk >> 4, off = (chunk & 15)*8;
      *(uint4*)&op[((size_t)(b*SPB + s0 + row))*512 + o0 + off] = *(const uint4*)&tile[row*128 + off];
    }
  } else {
    float* ftile = (float*)smem; // [64 o][64 s], one 64-channel half at a time
    float* op = (float*)outp;
    #pragma unroll
    for (int h=0; h<2; h++){
      if (wn == h){
        #pragma unroll
        for (int im=0;im<2;im++)
          #pragma unroll
          for (int in=0;in<4;in++){
            int ol = in*16 + l16;
            int og = o0 + wn*64 + ol;
            float sc = scale[og], bi = bias[og];
            float4v v;
            #pragma unroll
            for (int r=0;r<4;r++) v[r] = acc[im][in][r]*sc + bi;
            *(float4v*)&ftile[ol*64 + wm*32 + im*16 + quad*4] = v;
          }
      }
      __syncthreads();
      #pragma unroll
      for (int p=0;p<4;p++){
        int chunk = p*256 + tid;
        int row = chunk >> 4, off = (chunk & 15)*4;
        size_t g = ((size_t)(b*256 + o0 + h*64 + row))*SPB + s0 + off;
        float4v v = *(const float4v*)&ftile[row*64 + off];
        v.x += resid[g]; v.y += resid[g+1]; v.z += resid[g+2]; v.w += resid[g+3];
        *(float4v*)&op[g] = v;
      }
      __syncthreads();
    }
  }
}

extern "C" void kernel_launch(void* const* d_in, const int* in_sizes, int n_in,
                              void* d_out, int out_size, void* d_ws, size_t ws_size,
                              hipStream_t stream)
{
  const float* x  = (const float*)d_in[0];
  const float* w1 = (const float*)d_in[1];
  const float* b1 = (const float*)d_in[2];
  const float* g1 = (const float*)d_in[3];
  const float* be1= (const float*)d_in[4];
  const float* m1 = (const float*)d_in[5];
  const float* v1 = (const float*)d_in[6];
  const float* wg = (const float*)d_in[7];
  const float* bg = (const float*)d_in[8];
  const float* gg = (const float*)d_in[9];
  const float* beg= (const float*)d_in[10];
  const float* mg = (const float*)d_in[11];
  const float* vg = (const float*)d_in[12];
  const float* w2 = (const float*)d_in[13];
  const float* b2 = (const float*)d_in[14];
  const float* g2 = (const float*)d_in[15];
  const float* be2= (const float*)d_in[16];
  const float* m2 = (const float*)d_in[17];
  const float* v2 = (const float*)d_in[18];

  char* ws = (char*)d_ws;
  size_t off = 0;
  auto alloc = [&](size_t bytes){ void* p = ws + off; off += (bytes + 255) & ~(size_t)255; return p; };
  u16* xt    = (u16*)alloc((size_t)NB*SPB*256*2);   // x transposed, bf16
  u16* catt  = (u16*)alloc((size_t)NB*SPB*512*2);   // [h ; xj] transposed, bf16
  u16* gt    = (u16*)alloc((size_t)NB*SPB*512*2);   // gelu output transposed, bf16
  u16* w1b   = (u16*)alloc((size_t)65536*2);
  u16* wgb   = (u16*)alloc((size_t)262144*2);
  u16* w2b   = (u16*)alloc((size_t)131072*2);
  float* cst = (float*)alloc((size_t)2048*4);
  float* rmin= (float*)alloc((size_t)NB*2*56*256*4);
  float* cmin= (float*)alloc((size_t)NB*2*56*256*4);

  hipLaunchKernelGGL(prep_consts_k, dim3(1), dim3(512), 0, stream,
                     b1,g1,be1,m1,v1, bg,gg,beg,mg,vg, b2,g2,be2,m2,v2, cst);
  hipLaunchKernelGGL(conv_w_k, dim3(1024), dim3(256), 0, stream, w1,wg,w2, w1b,wgb,w2b);
  hipLaunchKernelGGL(transpose_x_k, dim3(98,8,8), dim3(32,8), 0, stream, x, xt);
  hipLaunchKernelGGL((gemm_k<256,1>), dim3(49,2,8), dim3(256), 0, stream,
                     xt, w1b, cst+0, cst+256, (void*)catt, (const float*)nullptr);
  hipLaunchKernelGGL(rowmin_k, dim3(NB*56), dim3(256), 0, stream, catt, rmin);
  hipLaunchKernelGGL(colmin_k, dim3(NB*56), dim3(256), 0, stream, catt, cmin);
  hipLaunchKernelGGL(xj_k, dim3(SPB, NB), dim3(256), 0, stream, catt, rmin, cmin);
  hipLaunchKernelGGL((gemm_k<512,2>), dim3(49,4,8), dim3(256), 0, stream,
                     catt, wgb, cst+512, cst+1024, (void*)gt, (const float*)nullptr);
  hipLaunchKernelGGL((gemm_k<512,3>), dim3(49,2,8), dim3(256), 0, stream,
                     gt, w2b, cst+1536, cst+1792, d_out, x);
}

// Round 2
// 205.892 us; speedup vs baseline: 1.0248x; 1.0248x over previous
//
#include <hip/hip_runtime.h>
#include <math.h>

#define SPB 3136      // spatial positions per batch (56*56)
#define NB 8
#define MTOT (NB*SPB) // 25088 = 196*128, flattened M across batch
#define EPS 1e-5f

typedef unsigned short u16;
typedef __attribute__((ext_vector_type(8))) short short8;
typedef __attribute__((ext_vector_type(4))) float float4v;

__device__ __forceinline__ float b2f(u16 v){ unsigned u=((unsigned)v)<<16; float f; __builtin_memcpy(&f,&u,4); return f; }
__device__ __forceinline__ u16 f2b(float f){ unsigned u; __builtin_memcpy(&u,&f,4); u += 0x7fffu + ((u>>16)&1u); return (u16)(u>>16); }
__device__ __forceinline__ float gelu_f(float z){ return 0.5f*z*(1.0f+erff(z*0.70710678118654752f)); }

// async global->LDS, 16B per lane; lds dest must be wave-uniform base + lane*16
__device__ __forceinline__ void gll16(const u16* g, u16* l){
  __builtin_amdgcn_global_load_lds((const __attribute__((address_space(1))) void*)g,
                                   (__attribute__((address_space(3))) void*)l, 16, 0, 0);
}

// ---- fold BN constants: s = g/sqrt(v+eps), t = b*s + be - m*s ----
// cst layout: s1[256] t1[256] sg[512] tg[512] s2[256] t2[256]
__global__ void prep_consts_k(const float* b1,const float* g1,const float* be1,const float* m1,const float* v1,
                              const float* bg,const float* gg,const float* beg,const float* mg,const float* vg,
                              const float* b2,const float* g2,const float* be2,const float* m2,const float* v2,
                              float* cst){
  int i = threadIdx.x;
  if (i < 256) {
    float s = g1[i]*rsqrtf(v1[i]+EPS);
    cst[i] = s; cst[256+i] = b1[i]*s + be1[i] - m1[i]*s;
    float s2 = g2[i]*rsqrtf(v2[i]+EPS);
    cst[1536+i] = s2; cst[1792+i] = b2[i]*s2 + be2[i] - m2[i]*s2;
  }
  float s = gg[i]*rsqrtf(vg[i]+EPS);
  cst[512+i] = s; cst[1024+i] = bg[i]*s + beg[i] - mg[i]*s;
}

__global__ void conv_w_k(const float* __restrict__ w1,const float* __restrict__ wg,const float* __restrict__ w2,
                         u16* __restrict__ w1b,u16* __restrict__ wgb,u16* __restrict__ w2b){
  int i = blockIdx.x*256 + threadIdx.x;
  if (i < 65536)  w1b[i] = f2b(w1[i]);
  if (i < 262144) wgb[i] = f2b(wg[i]);
  if (i < 131072) w2b[i] = f2b(w2[i]);
}

// x [b][c][s] fp32 -> xt [b][s][c] bf16
__global__ void transpose_x_k(const float* __restrict__ x, u16* __restrict__ xt){
  __shared__ float t[32][33];
  int b = blockIdx.z, ct = blockIdx.y, st = blockIdx.x;
  int ts = threadIdx.x, tc = threadIdx.y;
  #pragma unroll
  for (int i=0;i<4;i++){
    int c = tc + i*8;
    t[c][ts] = x[((size_t)(b*256 + ct*32 + c))*SPB + st*32 + ts];
  }
  __syncthreads();
  #pragma unroll
  for (int i=0;i<4;i++){
    int r = tc + i*8;
    xt[((size_t)(b*SPB + st*32 + r))*256 + ct*32 + ts] = f2b(t[ts][r]);
  }
}

// per (b,y): min over x of h, split by x-parity.  h = cat[...,0:256]
__global__ void rowmin_k(const u16* __restrict__ cat, float* __restrict__ rmin){
  int b = blockIdx.x/56, y = blockIdx.x%56, c = threadIdx.x;
  float mE=3.4e38f, mO=3.4e38f;
  const u16* base = cat + ((size_t)(b*SPB + y*56))*512 + c;
  for (int x=0;x<56;x+=2){
    mE = fminf(mE, b2f(base[(size_t)x*512]));
    mO = fminf(mO, b2f(base[(size_t)(x+1)*512]));
  }
  rmin[((size_t)(b*2+0)*56 + y)*256 + c]=mE;
  rmin[((size_t)(b*2+1)*56 + y)*256 + c]=mO;
}
// per (b,x): min over y of h, split by y-parity
__global__ void colmin_k(const u16* __restrict__ cat, float* __restrict__ cmin){
  int b = blockIdx.x/56, x = blockIdx.x%56, c = threadIdx.x;
  float mE=3.4e38f, mO=3.4e38f;
  const u16* base = cat + ((size_t)(b*SPB + x))*512 + c;
  for (int y=0;y<56;y+=2){
    mE = fminf(mE, b2f(base[(size_t)(y*56)*512]));
    mO = fminf(mO, b2f(base[(size_t)((y+1)*56)*512]));
  }
  cmin[((size_t)(b*2+0)*56 + x)*256 + c]=mE;
  cmin[((size_t)(b*2+1)*56 + x)*256 + c]=mO;
}
// xj = max(0, h - min(colMinP[y%2][x], rowMinP[x%2][y])) -> cat[...,256:512]
__global__ void xj_k(u16* __restrict__ cat, const float* __restrict__ rmin, const float* __restrict__ cmin){
  int b = blockIdx.y, s = blockIdx.x, c = threadIdx.x;
  int y = s/56, x = s%56;
  size_t idx = ((size_t)(b*SPB + s))*512;
  float h = b2f(cat[idx + c]);
  float m = fminf(cmin[((size_t)(b*2+(y&1))*56 + x)*256 + c],
                  rmin[((size_t)(b*2+(x&1))*56 + y)*256 + c]);
  cat[idx + 256 + c] = f2b(fmaxf(0.0f, h - m));
}

// GEMM: D[m][o] = sum_k Ain[m][k] * Wt[o][k]; M flattened over batch.
// Tiles BM=128(m) x BN=128(o) x BK=32; 4 waves, each 64x64 (4x4 MFMA tiles).
// Staging via global_load_lds width=16 (m97 structure).
// EPI 1: bf16( acc*s + t )              -> out [m][512] at col o0
// EPI 2: bf16( gelu(acc*s + t) )        -> out [m][512] at col o0
// EPI 3: fp32( acc*s + t + x[b][o][s] ) -> out [b][256][s]
template<int KTOT, int EPI>
__global__ __launch_bounds__(256) void gemm_k(
    const u16* __restrict__ Ain, const u16* __restrict__ Wt,
    const float* __restrict__ scale, const float* __restrict__ bias,
    void* __restrict__ outp, const float* __restrict__ resid)
{
  __shared__ __align__(16) u16 smem[16896];   // 33792 B (union: staging / epilogue)
  u16* As = smem;          // [128][32] bf16, chunk-ordered (row-major, unpadded)
  u16* Bs = smem + 4096;   // [128][32]
  const int tid = threadIdx.x;
  const int m0 = blockIdx.x * 128;
  const int o0 = blockIdx.y * 128;
  const int lane = tid & 63, wid = tid >> 6;
  const int quad = lane >> 4, l16 = lane & 15;
  const int wm = wid & 1, wn = wid >> 1;

  float4v acc[4][4];
  #pragma unroll
  for (int i=0;i<4;i++)
    #pragma unroll
    for (int j=0;j<4;j++) acc[i][j] = (float4v){0.f,0.f,0.f,0.f};

  // staging: chunk c in [0,512): row=c>>2, q=c&3; thread t handles chunks t and 256+t
  const int row = tid >> 2, q8 = (tid & 3) * 8;
  const u16* ga0 = Ain + ((size_t)(m0 + row))*KTOT + q8;
  const u16* ga1 = ga0 + (size_t)64*KTOT;
  const u16* gb0 = Wt  + ((size_t)(o0 + row))*KTOT + q8;
  const u16* gb1 = gb0 + (size_t)64*KTOT;
  u16* la0 = As + tid*8;
  u16* la1 = As + 2048 + tid*8;
  u16* lb0 = Bs + tid*8;
  u16* lb1 = Bs + 2048 + tid*8;

  for (int kt = 0; kt < KTOT; kt += 32) {
    gll16(ga0 + kt, la0);
    gll16(ga1 + kt, la1);
    gll16(gb0 + kt, lb0);
    gll16(gb1 + kt, lb1);
    __syncthreads();
    short8 af[4], bfr[4];
    #pragma unroll
    for (int im=0;im<4;im++) af[im]  = *(const short8*)&As[(wm*64+im*16+l16)*32 + quad*8];
    #pragma unroll
    for (int in=0;in<4;in++) bfr[in] = *(const short8*)&Bs[(wn*64+in*16+l16)*32 + quad*8];
    #pragma unroll
    for (int im=0;im<4;im++)
      #pragma unroll
      for (int in=0;in<4;in++)
        acc[im][in] = __builtin_amdgcn_mfma_f32_16x16x32_bf16(af[im], bfr[in], acc[im][in], 0, 0, 0);
    __syncthreads();
  }

  if (EPI == 1 || EPI == 2) {
    u16* tile = smem; // [128 m][128 o]
    #pragma unroll
    for (int im=0;im<4;im++)
      #pragma unroll
      for (int in=0;in<4;in++){
        int ol = wn*64 + in*16 + l16;
        float sc = scale[o0+ol], bi = bias[o0+ol];
        #pragma unroll
        for (int r=0;r<4;r++){
          float v = acc[im][in][r]*sc + bi;
          if (EPI==2) v = gelu_f(v);
          tile[(wm*64+im*16+quad*4+r)*128 + ol] = f2b(v);
        }
      }
    __syncthreads();
    u16* op = (u16*)outp;
    #pragma unroll
    for (int p=0;p<8;p++){
      int chunk = p*256 + tid;
      int rr = chunk >> 4, off = (chunk & 15)*8;
      *(uint4*)&op[((size_t)(m0 + rr))*512 + o0 + off] = *(const uint4*)&tile[rr*128 + off];
    }
  } else {
    float* ftile = (float*)smem; // [64 o][132 m] padded, one 64-chan half at a time
    float* op = (float*)outp;
    #pragma unroll
    for (int h=0; h<2; h++){
      if (wn == h){
        #pragma unroll
        for (int im=0;im<4;im++)
          #pragma unroll
          for (int in=0;in<4;in++){
            int c64 = in*16 + l16;
            int og = o0 + h*64 + c64;
            float sc = scale[og], bi = bias[og];
            float4v v;
            #pragma unroll
            for (int r=0;r<4;r++) v[r] = acc[im][in][r]*sc + bi;
            *(float4v*)&ftile[c64*132 + wm*64 + im*16 + quad*4] = v;
          }
      }
      __syncthreads();
      #pragma unroll
      for (int p=0;p<8;p++){
        int chunk = p*256 + tid;
        int rr = chunk >> 5, off = (chunk & 31)*4;
        int m = m0 + off;
        int b = m / SPB, s = m - b*SPB;
        size_t g = ((size_t)(b*256 + o0 + h*64 + rr))*SPB + s;
        float4v v = *(const float4v*)&ftile[rr*132 + off];
        v.x += resid[g]; v.y += resid[g+1]; v.z += resid[g+2]; v.w += resid[g+3];
        *(float4v*)&op[g] = v;
      }
      __syncthreads();
    }
  }
}

extern "C" void kernel_launch(void* const* d_in, const int* in_sizes, int n_in,
                              void* d_out, int out_size, void* d_ws, size_t ws_size,
                              hipStream_t stream)
{
  const float* x  = (const float*)d_in[0];
  const float* w1 = (const float*)d_in[1];
  const float* b1 = (const float*)d_in[2];
  const float* g1 = (const float*)d_in[3];
  const float* be1= (const float*)d_in[4];
  const float* m1 = (const float*)d_in[5];
  const float* v1 = (const float*)d_in[6];
  const float* wg = (const float*)d_in[7];
  const float* bg = (const float*)d_in[8];
  const float* gg = (const float*)d_in[9];
  const float* beg= (const float*)d_in[10];
  const float* mg = (const float*)d_in[11];
  const float* vg = (const float*)d_in[12];
  const float* w2 = (const float*)d_in[13];
  const float* b2 = (const float*)d_in[14];
  const float* g2 = (const float*)d_in[15];
  const float* be2= (const float*)d_in[16];
  const float* m2 = (const float*)d_in[17];
  const float* v2 = (const float*)d_in[18];

  char* ws = (char*)d_ws;
  size_t off = 0;
  auto alloc = [&](size_t bytes){ void* p = ws + off; off += (bytes + 255) & ~(size_t)255; return p; };
  u16* xt    = (u16*)alloc((size_t)MTOT*256*2);   // x transposed, bf16
  u16* catt  = (u16*)alloc((size_t)MTOT*512*2);   // [h ; xj] transposed, bf16
  u16* gt    = (u16*)alloc((size_t)MTOT*512*2);   // gelu output transposed, bf16
  u16* w1b   = (u16*)alloc((size_t)65536*2);
  u16* wgb   = (u16*)alloc((size_t)262144*2);
  u16* w2b   = (u16*)alloc((size_t)131072*2);
  float* cst = (float*)alloc((size_t)2048*4);
  float* rmin= (float*)alloc((size_t)NB*2*56*256*4);
  float* cmin= (float*)alloc((size_t)NB*2*56*256*4);

  hipLaunchKernelGGL(prep_consts_k, dim3(1), dim3(512), 0, stream,
                     b1,g1,be1,m1,v1, bg,gg,beg,mg,vg, b2,g2,be2,m2,v2, cst);
  hipLaunchKernelGGL(conv_w_k, dim3(1024), dim3(256), 0, stream, w1,wg,w2, w1b,wgb,w2b);
  hipLaunchKernelGGL(transpose_x_k, dim3(98,8,8), dim3(32,8), 0, stream, x, xt);
  hipLaunchKernelGGL((gemm_k<256,1>), dim3(196,2), dim3(256), 0, stream,
                     xt, w1b, cst+0, cst+256, (void*)catt, (const float*)nullptr);
  hipLaunchKernelGGL(rowmin_k, dim3(NB*56), dim3(256), 0, stream, catt, rmin);
  hipLaunchKernelGGL(colmin_k, dim3(NB*56), dim3(256), 0, stream, catt, cmin);
  hipLaunchKernelGGL(xj_k, dim3(SPB, NB), dim3(256), 0, stream, catt, rmin, cmin);
  hipLaunchKernelGGL((gemm_k<512,2>), dim3(196,4), dim3(256), 0, stream,
                     catt, wgb, cst+512, cst+1024, (void*)gt, (const float*)nullptr);
  hipLaunchKernelGGL((gemm_k<512,3>), dim3(196,2), dim3(256), 0, stream,
                     gt, w2b, cst+1536, cst+1792, d_out, x);
}